// Round 1
// baseline (1793.042 us; speedup 1.0000x reference)
//
#include <hip/hip_runtime.h>

#define D 128
#define NB 32

// ---------------------------------------------------------------------------
// Kernel 1: per-edge scatter.  32 threads per edge; thread c handles float4
// chunk c of the 128-dim row.  Atomic f32 adds into sum[dst], lane c==0
// counts the edge for the mean.
// ---------------------------------------------------------------------------
__global__ __launch_bounds__(256) void edge_scatter_kernel(
    const float* __restrict__ h, const float* __restrict__ alpha,
    const float* __restrict__ ew, const int* __restrict__ node_id,
    const int* __restrict__ esrc, const int* __restrict__ edst,
    float* __restrict__ sum, float* __restrict__ cnt,
    int E, int gene_num) {
  int gid = blockIdx.x * blockDim.x + threadIdx.x;
  int e = gid >> 5;
  int c = gid & 31;
  if (e >= E) return;
  int src = esrc[e];
  int dst = edst[e];
  int sid = node_id[src];
  int did = node_id[dst];
  // reference: default cell self-loop (gene_num+1); gene->cell uses beta[src];
  // cell->gene uses beta[dst]; gene->gene uses alpha (gene_num). Mutually excl.
  int idx;
  if (sid >= 0) idx = (did >= 0) ? gene_num : sid;
  else          idx = (did >= 0) ? did : (gene_num + 1);
  float coeff = alpha[idx] * ew[e];
  float4 hv = ((const float4*)h)[(size_t)src * (D / 4) + c];
  float* sp = sum + (size_t)dst * D + c * 4;
  atomicAdd(sp + 0, hv.x * coeff);
  atomicAdd(sp + 1, hv.y * coeff);
  atomicAdd(sp + 2, hv.z * coeff);
  atomicAdd(sp + 3, hv.w * coeff);
  if (c == 0) atomicAdd(cnt + dst, 1.0f);
}

// ---------------------------------------------------------------------------
// Kernel 2: neigh = sum/max(cnt,1);  out = relu(neigh @ W.T + b)
// Block: 256 threads, NB=32 nodes.  W staged in LDS in two 64-row halves
// (32 KB, XOR-swizzled so strided row reads are bank-conflict-free).
// neigh staged once (stride-33 float4 rows to kill the 4-way broadcast
// conflict).  Each thread: 4 j (j = jh*64 + jq + 16*jj) x 2 nodes.
// ---------------------------------------------------------------------------
__global__ __launch_bounds__(256) void mlp_kernel(
    const float* __restrict__ sum, const float* __restrict__ cnt,
    const float* __restrict__ W, const float* __restrict__ bias,
    float* __restrict__ out, int N) {
  __shared__ float4 Wl[64 * 32];     // 32 KB, rows swizzled: col = d4 ^ (r&7)
  __shared__ float4 NBl[NB * 33];    // ~16.9 KB, row stride 33 f4

  int t = threadIdx.x;
  int n0 = blockIdx.x * NB;

  // stage neigh (mean) for NB nodes: NB*32 f4 = 1024 f4, 4 per thread
  for (int i = 0; i < (NB * 32) / 256; ++i) {
    int idx = t + i * 256;
    int n = idx >> 5, d4 = idx & 31;
    int ng = n0 + n;
    float4 v = make_float4(0.f, 0.f, 0.f, 0.f);
    if (ng < N) {
      float cn = cnt[ng];
      float r = 1.0f / fmaxf(cn, 1.0f);
      float4 s = ((const float4*)sum)[(size_t)ng * 32 + d4];
      v = make_float4(s.x * r, s.y * r, s.z * r, s.w * r);
    }
    NBl[n * 33 + d4] = v;
  }

  int jq = t & 15;       // 0..15
  int g = t >> 4;        // 0..15 -> nodes 2g, 2g+1

  for (int jh = 0; jh < 2; ++jh) {
    __syncthreads();     // protect Wl reuse (and NBl readiness on jh==0)
    // stage 64 rows of W: 2048 f4, 8 per thread (coalesced global float4)
    for (int i = 0; i < 8; ++i) {
      int idx = t + i * 256;
      int r = idx >> 5, d4 = idx & 31;
      float4 w = ((const float4*)W)[(size_t)(jh * 64 + r) * 32 + d4];
      Wl[r * 32 + (d4 ^ (r & 7))] = w;
    }
    __syncthreads();

    float acc[4][2];
#pragma unroll
    for (int jj = 0; jj < 4; ++jj)
#pragma unroll
      for (int nn = 0; nn < 2; ++nn) acc[jj][nn] = 0.f;

#pragma unroll 8
    for (int d4 = 0; d4 < 32; ++d4) {
      float4 nbv0 = NBl[(2 * g + 0) * 33 + d4];
      float4 nbv1 = NBl[(2 * g + 1) * 33 + d4];
#pragma unroll
      for (int jj = 0; jj < 4; ++jj) {
        int r = jq + 16 * jj;
        float4 w = Wl[r * 32 + (d4 ^ (r & 7))];
        acc[jj][0] += w.x * nbv0.x + w.y * nbv0.y + w.z * nbv0.z + w.w * nbv0.w;
        acc[jj][1] += w.x * nbv1.x + w.y * nbv1.y + w.z * nbv1.z + w.w * nbv1.w;
      }
    }

#pragma unroll
    for (int jj = 0; jj < 4; ++jj) {
      int j = jh * 64 + jq + 16 * jj;
      float bj = bias[j];
#pragma unroll
      for (int nn = 0; nn < 2; ++nn) {
        int ng = n0 + 2 * g + nn;
        if (ng < N) out[(size_t)ng * D + j] = fmaxf(acc[jj][nn] + bj, 0.0f);
      }
    }
  }
}

extern "C" void kernel_launch(void* const* d_in, const int* in_sizes, int n_in,
                              void* d_out, int out_size, void* d_ws, size_t ws_size,
                              hipStream_t stream) {
  const float* h     = (const float*)d_in[0];
  const float* alpha = (const float*)d_in[1];
  const float* ew    = (const float*)d_in[2];
  const float* W     = (const float*)d_in[3];
  const float* bias  = (const float*)d_in[4];
  const int* node_id = (const int*)d_in[5];
  const int* esrc    = (const int*)d_in[6];
  const int* edst    = (const int*)d_in[7];
  float* out = (float*)d_out;

  int E = in_sizes[2];
  int N = in_sizes[5];
  int gene_num = in_sizes[1] - 2;

  float* sum = (float*)d_ws;                    // N*D floats
  float* cnt = sum + (size_t)N * D;             // N floats
  size_t zero_bytes = ((size_t)N * D + N) * sizeof(float);
  if (ws_size < zero_bytes) return;             // not enough scratch (shouldn't happen)

  hipMemsetAsync(d_ws, 0, zero_bytes, stream);

  {
    long long total = (long long)E * 32;
    int blocks = (int)((total + 255) / 256);
    edge_scatter_kernel<<<blocks, 256, 0, stream>>>(h, alpha, ew, node_id,
                                                    esrc, edst, sum, cnt,
                                                    E, gene_num);
  }
  {
    int blocks = (N + NB - 1) / NB;
    mlp_kernel<<<blocks, 256, 0, stream>>>(sum, cnt, W, bias, out, N);
  }
}

// Round 2
// 348.391 us; speedup vs baseline: 5.1466x; 5.1466x over previous
//
#include <hip/hip_runtime.h>

#define D 128
#define NB 32

// ---------------------------------------------------------------------------
// Pass A: histogram of edge destinations -> deg[dst]
// ---------------------------------------------------------------------------
__global__ __launch_bounds__(256) void hist_kernel(
    const int* __restrict__ edst, int* __restrict__ deg, int E) {
  int e = blockIdx.x * blockDim.x + threadIdx.x;
  if (e >= E) return;
  atomicAdd(deg + edst[e], 1);
}

// ---------------------------------------------------------------------------
// Pass B: single-block scan.  cur[n] = exclusive prefix (scatter cursor),
// offs[n] = inclusive prefix (bucket end).
// ---------------------------------------------------------------------------
__global__ __launch_bounds__(1024) void scan_kernel(
    const int* __restrict__ deg, int* __restrict__ cur,
    int* __restrict__ offs, int N) {
  __shared__ int ts[1024];
  int t = threadIdx.x;
  int chunk = (N + 1023) / 1024;
  int base = t * chunk;
  int s = 0;
  for (int i = 0; i < chunk; ++i) {
    int idx = base + i;
    if (idx < N) s += deg[idx];
  }
  ts[t] = s;
  __syncthreads();
  for (int off = 1; off < 1024; off <<= 1) {
    int v = (t >= off) ? ts[t - off] : 0;
    __syncthreads();
    ts[t] += v;
    __syncthreads();
  }
  int run = (t == 0) ? 0 : ts[t - 1];
  for (int i = 0; i < chunk; ++i) {
    int idx = base + i;
    if (idx < N) {
      cur[idx] = run;
      run += deg[idx];
      offs[idx] = run;
    }
  }
}

// ---------------------------------------------------------------------------
// Pass C: scatter edges into dst-sorted record array {src, coeff}.
// ---------------------------------------------------------------------------
__global__ __launch_bounds__(256) void scatter_kernel(
    const float* __restrict__ alpha, const float* __restrict__ ew,
    const int* __restrict__ node_id, const int* __restrict__ esrc,
    const int* __restrict__ edst, int* __restrict__ cur,
    int2* __restrict__ recs, int E, int gene_num) {
  int e = blockIdx.x * blockDim.x + threadIdx.x;
  if (e >= E) return;
  int src = esrc[e];
  int dst = edst[e];
  int sid = node_id[src];
  int did = node_id[dst];
  int idx;
  if (sid >= 0) idx = (did >= 0) ? gene_num : sid;
  else          idx = (did >= 0) ? did : (gene_num + 1);
  float coeff = alpha[idx] * ew[e];
  int pos = atomicAdd(cur + dst, 1);
  recs[pos] = make_int2(src, __float_as_int(coeff));
}

// ---------------------------------------------------------------------------
// Pass D: one wave per dst node.  Lane l owns float2 chunk l of the 128-dim
// row.  Wave loads up to 64 records coalesced, broadcasts each via shfl,
// gathers h[src] (512B contiguous per edge), accumulates in registers,
// writes the mean row once.  neigh -> d_out (overwritten by MLP later).
// ---------------------------------------------------------------------------
__global__ __launch_bounds__(256) void accumulate_kernel(
    const float* __restrict__ h, const int2* __restrict__ recs,
    const int* __restrict__ offs, float* __restrict__ neigh, int N) {
  int wid = (blockIdx.x * blockDim.x + threadIdx.x) >> 6;
  int l = threadIdx.x & 63;
  if (wid >= N) return;
  int start = (wid == 0) ? 0 : offs[wid - 1];
  int end = offs[wid];
  float ax = 0.f, ay = 0.f;
  const float* hb = h + 2 * l;
  for (int i = start; i < end; i += 64) {
    int m = end - i;
    if (m > 64) m = 64;
    int2 r = make_int2(0, 0);
    if (l < m) r = recs[i + l];
    for (int k = 0; k < m; ++k) {
      int src = __shfl(r.x, k);
      float cf = __int_as_float(__shfl(r.y, k));
      float2 hv = *(const float2*)(hb + (size_t)src * D);
      ax += cf * hv.x;
      ay += cf * hv.y;
    }
  }
  int degn = end - start;
  float inv = 1.0f / (float)(degn > 0 ? degn : 1);
  ((float2*)neigh)[(size_t)wid * (D / 2) + l] = make_float2(ax * inv, ay * inv);
}

// ---------------------------------------------------------------------------
// MLP: out = relu(neigh @ W.T + b), in-place on d_out (neigh staged to LDS
// per block before any write).  W in LDS, XOR-swizzled; neigh rows padded.
// ---------------------------------------------------------------------------
__global__ __launch_bounds__(256) void mlp_kernel(
    const float* __restrict__ neigh, const float* __restrict__ W,
    const float* __restrict__ bias, float* __restrict__ out, int N) {
  __shared__ float4 Wl[64 * 32];     // 32 KB, col = d4 ^ (r&7)
  __shared__ float4 NBl[NB * 33];    // row stride 33 f4

  int t = threadIdx.x;
  int n0 = blockIdx.x * NB;

  for (int i = 0; i < (NB * 32) / 256; ++i) {
    int idx = t + i * 256;
    int n = idx >> 5, d4 = idx & 31;
    int ng = n0 + n;
    float4 v = make_float4(0.f, 0.f, 0.f, 0.f);
    if (ng < N) v = ((const float4*)neigh)[(size_t)ng * 32 + d4];
    NBl[n * 33 + d4] = v;
  }

  int jq = t & 15;
  int g = t >> 4;

  for (int jh = 0; jh < 2; ++jh) {
    __syncthreads();
    for (int i = 0; i < 8; ++i) {
      int idx = t + i * 256;
      int r = idx >> 5, d4 = idx & 31;
      float4 w = ((const float4*)W)[(size_t)(jh * 64 + r) * 32 + d4];
      Wl[r * 32 + (d4 ^ (r & 7))] = w;
    }
    __syncthreads();

    float acc[4][2];
#pragma unroll
    for (int jj = 0; jj < 4; ++jj)
#pragma unroll
      for (int nn = 0; nn < 2; ++nn) acc[jj][nn] = 0.f;

#pragma unroll 8
    for (int d4 = 0; d4 < 32; ++d4) {
      float4 nbv0 = NBl[(2 * g + 0) * 33 + d4];
      float4 nbv1 = NBl[(2 * g + 1) * 33 + d4];
#pragma unroll
      for (int jj = 0; jj < 4; ++jj) {
        int r = jq + 16 * jj;
        float4 w = Wl[r * 32 + (d4 ^ (r & 7))];
        acc[jj][0] += w.x * nbv0.x + w.y * nbv0.y + w.z * nbv0.z + w.w * nbv0.w;
        acc[jj][1] += w.x * nbv1.x + w.y * nbv1.y + w.z * nbv1.z + w.w * nbv1.w;
      }
    }

#pragma unroll
    for (int jj = 0; jj < 4; ++jj) {
      int j = jh * 64 + jq + 16 * jj;
      float bj = bias[j];
#pragma unroll
      for (int nn = 0; nn < 2; ++nn) {
        int ng = n0 + 2 * g + nn;
        if (ng < N) out[(size_t)ng * D + j] = fmaxf(acc[jj][nn] + bj, 0.0f);
      }
    }
  }
}

extern "C" void kernel_launch(void* const* d_in, const int* in_sizes, int n_in,
                              void* d_out, int out_size, void* d_ws, size_t ws_size,
                              hipStream_t stream) {
  const float* h     = (const float*)d_in[0];
  const float* alpha = (const float*)d_in[1];
  const float* ew    = (const float*)d_in[2];
  const float* W     = (const float*)d_in[3];
  const float* bias  = (const float*)d_in[4];
  const int* node_id = (const int*)d_in[5];
  const int* esrc    = (const int*)d_in[6];
  const int* edst    = (const int*)d_in[7];
  float* out = (float*)d_out;

  int E = in_sizes[2];
  int N = in_sizes[5];
  int gene_num = in_sizes[1] - 2;

  // workspace layout
  int* deg  = (int*)d_ws;                       // N
  int* cur  = deg + N;                          // N
  int* offs = cur + N;                          // N
  size_t rec_off = ((size_t)(3 * N) * sizeof(int) + 15) & ~(size_t)15;
  int2* recs = (int2*)((char*)d_ws + rec_off);  // E * 8B
  size_t need = rec_off + (size_t)E * sizeof(int2);
  if (ws_size < need) return;

  hipMemsetAsync(deg, 0, (size_t)N * sizeof(int), stream);

  {
    int blocks = (E + 255) / 256;
    hist_kernel<<<blocks, 256, 0, stream>>>(edst, deg, E);
  }
  scan_kernel<<<1, 1024, 0, stream>>>(deg, cur, offs, N);
  {
    int blocks = (E + 255) / 256;
    scatter_kernel<<<blocks, 256, 0, stream>>>(alpha, ew, node_id, esrc, edst,
                                               cur, recs, E, gene_num);
  }
  {
    long long total = (long long)N * 64;
    int blocks = (int)((total + 255) / 256);
    accumulate_kernel<<<blocks, 256, 0, stream>>>(h, recs, offs, out, N);
  }
  {
    int blocks = (N + NB - 1) / NB;
    mlp_kernel<<<blocks, 256, 0, stream>>>(out, W, bias, out, N);
  }
}

// Round 3
// 235.226 us; speedup vs baseline: 7.6226x; 1.4811x over previous
//
#include <hip/hip_runtime.h>

#define D 128
#define NB 32

// ---------------------------------------------------------------------------
// Pass A: histogram of edge destinations -> deg[dst]
// ---------------------------------------------------------------------------
__global__ __launch_bounds__(256) void hist_kernel(
    const int* __restrict__ edst, int* __restrict__ deg, int E) {
  int e = blockIdx.x * blockDim.x + threadIdx.x;
  if (e >= E) return;
  atomicAdd(deg + edst[e], 1);
}

// ---------------------------------------------------------------------------
// Pass B1: per-block (256-element) sums of deg -> bsum[b]
// ---------------------------------------------------------------------------
__global__ __launch_bounds__(256) void scan_reduce_kernel(
    const int* __restrict__ deg, int* __restrict__ bsum, int N) {
  __shared__ int ts[256];
  int t = threadIdx.x;
  int i = blockIdx.x * 256 + t;
  ts[t] = (i < N) ? deg[i] : 0;
  __syncthreads();
  for (int off = 128; off > 0; off >>= 1) {
    if (t < off) ts[t] += ts[t + off];
    __syncthreads();
  }
  if (t == 0) bsum[blockIdx.x] = ts[0];
}

// ---------------------------------------------------------------------------
// Pass B2: single block scans block sums (nb <= 256) -> exclusive boff[b]
// ---------------------------------------------------------------------------
__global__ __launch_bounds__(256) void scan_blocksums_kernel(
    const int* __restrict__ bsum, int* __restrict__ boff, int nb) {
  __shared__ int ts[256];
  int t = threadIdx.x;
  ts[t] = (t < nb) ? bsum[t] : 0;
  __syncthreads();
  for (int off = 1; off < 256; off <<= 1) {
    int v = (t >= off) ? ts[t - off] : 0;
    __syncthreads();
    ts[t] += v;
    __syncthreads();
  }
  if (t < nb) boff[t] = (t == 0) ? 0 : ts[t - 1];
}

// ---------------------------------------------------------------------------
// Pass B3: per-block 256-element scan + block offset -> cur (excl), offs (incl)
// ---------------------------------------------------------------------------
__global__ __launch_bounds__(256) void scan_final_kernel(
    const int* __restrict__ deg, const int* __restrict__ boff,
    int* __restrict__ cur, int* __restrict__ offs, int N) {
  __shared__ int ts[256];
  int t = threadIdx.x;
  int i = blockIdx.x * 256 + t;
  int v = (i < N) ? deg[i] : 0;
  ts[t] = v;
  __syncthreads();
  for (int off = 1; off < 256; off <<= 1) {
    int x = (t >= off) ? ts[t - off] : 0;
    __syncthreads();
    ts[t] += x;
    __syncthreads();
  }
  if (i < N) {
    int incl = ts[t] + boff[blockIdx.x];
    cur[i] = incl - v;
    offs[i] = incl;
  }
}

// ---------------------------------------------------------------------------
// Pass C: scatter edges into dst-sorted record array {src, coeff}.
// ---------------------------------------------------------------------------
__global__ __launch_bounds__(256) void scatter_kernel(
    const float* __restrict__ alpha, const float* __restrict__ ew,
    const int* __restrict__ node_id, const int* __restrict__ esrc,
    const int* __restrict__ edst, int* __restrict__ cur,
    int2* __restrict__ recs, int E, int gene_num) {
  int e = blockIdx.x * blockDim.x + threadIdx.x;
  if (e >= E) return;
  int src = esrc[e];
  int dst = edst[e];
  int sid = node_id[src];
  int did = node_id[dst];
  int idx;
  if (sid >= 0) idx = (did >= 0) ? gene_num : sid;
  else          idx = (did >= 0) ? did : (gene_num + 1);
  float coeff = alpha[idx] * ew[e];
  int pos = atomicAdd(cur + dst, 1);
  recs[pos] = make_int2(src, __float_as_int(coeff));
}

// ---------------------------------------------------------------------------
// Pass D: one wave per dst node.  Lane l owns float2 chunk l of the 128-dim
// row.  Wave loads up to 64 records coalesced, broadcasts each via shfl,
// gathers h[src] (512B contiguous per edge), accumulates in registers,
// writes the mean row once.  neigh -> d_out (overwritten by MLP later).
// ---------------------------------------------------------------------------
__global__ __launch_bounds__(256) void accumulate_kernel(
    const float* __restrict__ h, const int2* __restrict__ recs,
    const int* __restrict__ offs, float* __restrict__ neigh, int N) {
  int wid = (blockIdx.x * blockDim.x + threadIdx.x) >> 6;
  int l = threadIdx.x & 63;
  if (wid >= N) return;
  int start = (wid == 0) ? 0 : offs[wid - 1];
  int end = offs[wid];
  float ax = 0.f, ay = 0.f;
  const float* hb = h + 2 * l;
  for (int i = start; i < end; i += 64) {
    int m = end - i;
    if (m > 64) m = 64;
    int2 r = make_int2(0, 0);
    if (l < m) r = recs[i + l];
    for (int k = 0; k < m; ++k) {
      int src = __shfl(r.x, k);
      float cf = __int_as_float(__shfl(r.y, k));
      float2 hv = *(const float2*)(hb + (size_t)src * D);
      ax += cf * hv.x;
      ay += cf * hv.y;
    }
  }
  int degn = end - start;
  float inv = 1.0f / (float)(degn > 0 ? degn : 1);
  ((float2*)neigh)[(size_t)wid * (D / 2) + l] = make_float2(ax * inv, ay * inv);
}

// ---------------------------------------------------------------------------
// MLP: out = relu(neigh @ W.T + b), in-place on d_out (neigh staged to LDS
// per block before any write).  W in LDS, XOR-swizzled; neigh rows padded.
// ---------------------------------------------------------------------------
__global__ __launch_bounds__(256) void mlp_kernel(
    const float* __restrict__ neigh, const float* __restrict__ W,
    const float* __restrict__ bias, float* __restrict__ out, int N) {
  __shared__ float4 Wl[64 * 32];     // 32 KB, col = d4 ^ (r&7)
  __shared__ float4 NBl[NB * 33];    // row stride 33 f4

  int t = threadIdx.x;
  int n0 = blockIdx.x * NB;

  for (int i = 0; i < (NB * 32) / 256; ++i) {
    int idx = t + i * 256;
    int n = idx >> 5, d4 = idx & 31;
    int ng = n0 + n;
    float4 v = make_float4(0.f, 0.f, 0.f, 0.f);
    if (ng < N) v = ((const float4*)neigh)[(size_t)ng * 32 + d4];
    NBl[n * 33 + d4] = v;
  }

  int jq = t & 15;
  int g = t >> 4;

  for (int jh = 0; jh < 2; ++jh) {
    __syncthreads();
    for (int i = 0; i < 8; ++i) {
      int idx = t + i * 256;
      int r = idx >> 5, d4 = idx & 31;
      float4 w = ((const float4*)W)[(size_t)(jh * 64 + r) * 32 + d4];
      Wl[r * 32 + (d4 ^ (r & 7))] = w;
    }
    __syncthreads();

    float acc[4][2];
#pragma unroll
    for (int jj = 0; jj < 4; ++jj)
#pragma unroll
      for (int nn = 0; nn < 2; ++nn) acc[jj][nn] = 0.f;

#pragma unroll 8
    for (int d4 = 0; d4 < 32; ++d4) {
      float4 nbv0 = NBl[(2 * g + 0) * 33 + d4];
      float4 nbv1 = NBl[(2 * g + 1) * 33 + d4];
#pragma unroll
      for (int jj = 0; jj < 4; ++jj) {
        int r = jq + 16 * jj;
        float4 w = Wl[r * 32 + (d4 ^ (r & 7))];
        acc[jj][0] += w.x * nbv0.x + w.y * nbv0.y + w.z * nbv0.z + w.w * nbv0.w;
        acc[jj][1] += w.x * nbv1.x + w.y * nbv1.y + w.z * nbv1.z + w.w * nbv1.w;
      }
    }

#pragma unroll
    for (int jj = 0; jj < 4; ++jj) {
      int j = jh * 64 + jq + 16 * jj;
      float bj = bias[j];
#pragma unroll
      for (int nn = 0; nn < 2; ++nn) {
        int ng = n0 + 2 * g + nn;
        if (ng < N) out[(size_t)ng * D + j] = fmaxf(acc[jj][nn] + bj, 0.0f);
      }
    }
  }
}

extern "C" void kernel_launch(void* const* d_in, const int* in_sizes, int n_in,
                              void* d_out, int out_size, void* d_ws, size_t ws_size,
                              hipStream_t stream) {
  const float* h     = (const float*)d_in[0];
  const float* alpha = (const float*)d_in[1];
  const float* ew    = (const float*)d_in[2];
  const float* W     = (const float*)d_in[3];
  const float* bias  = (const float*)d_in[4];
  const int* node_id = (const int*)d_in[5];
  const int* esrc    = (const int*)d_in[6];
  const int* edst    = (const int*)d_in[7];
  float* out = (float*)d_out;

  int E = in_sizes[2];
  int N = in_sizes[5];
  int gene_num = in_sizes[1] - 2;
  int nb = (N + 255) / 256;   // 196 for N=50000, must be <= 256

  // workspace layout
  int* deg  = (int*)d_ws;                       // N
  int* cur  = deg + N;                          // N
  int* offs = cur + N;                          // N
  int* bsum = offs + N;                         // 256
  int* boff = bsum + 256;                       // 256
  size_t rec_off = (((size_t)(3 * N) + 512) * sizeof(int) + 15) & ~(size_t)15;
  int2* recs = (int2*)((char*)d_ws + rec_off);  // E * 8B
  size_t need = rec_off + (size_t)E * sizeof(int2);
  if (ws_size < need) return;

  hipMemsetAsync(deg, 0, (size_t)N * sizeof(int), stream);

  {
    int blocks = (E + 255) / 256;
    hist_kernel<<<blocks, 256, 0, stream>>>(edst, deg, E);
  }
  scan_reduce_kernel<<<nb, 256, 0, stream>>>(deg, bsum, N);
  scan_blocksums_kernel<<<1, 256, 0, stream>>>(bsum, boff, nb);
  scan_final_kernel<<<nb, 256, 0, stream>>>(deg, boff, cur, offs, N);
  {
    int blocks = (E + 255) / 256;
    scatter_kernel<<<blocks, 256, 0, stream>>>(alpha, ew, node_id, esrc, edst,
                                               cur, recs, E, gene_num);
  }
  {
    long long total = (long long)N * 64;
    int blocks = (int)((total + 255) / 256);
    accumulate_kernel<<<blocks, 256, 0, stream>>>(h, recs, offs, out, N);
  }
  {
    int blocks = (N + NB - 1) / NB;
    mlp_kernel<<<blocks, 256, 0, stream>>>(out, W, bias, out, N);
  }
}

// Round 4
// 211.369 us; speedup vs baseline: 8.4830x; 1.1129x over previous
//
#include <hip/hip_runtime.h>

#define D 128
#define NB 32

// ---------------------------------------------------------------------------
// Pass 0: convert h (f32) -> h16 (bf16, RNE).  4 elements / thread.
// ---------------------------------------------------------------------------
__global__ __launch_bounds__(256) void cvt_kernel(
    const float* __restrict__ h, unsigned short* __restrict__ h16, int total4) {
  int i = blockIdx.x * blockDim.x + threadIdx.x;
  if (i >= total4) return;
  float4 v = ((const float4*)h)[i];
  unsigned int u0 = __float_as_uint(v.x), u1 = __float_as_uint(v.y);
  unsigned int u2 = __float_as_uint(v.z), u3 = __float_as_uint(v.w);
  u0 = (u0 + 0x7fffu + ((u0 >> 16) & 1)) >> 16;
  u1 = (u1 + 0x7fffu + ((u1 >> 16) & 1)) >> 16;
  u2 = (u2 + 0x7fffu + ((u2 >> 16) & 1)) >> 16;
  u3 = (u3 + 0x7fffu + ((u3 >> 16) & 1)) >> 16;
  ushort4 o;
  o.x = (unsigned short)u0; o.y = (unsigned short)u1;
  o.z = (unsigned short)u2; o.w = (unsigned short)u3;
  ((ushort4*)h16)[i] = o;
}

// ---------------------------------------------------------------------------
// Pass A: histogram of edge destinations -> deg[dst].  4 edges / thread.
// ---------------------------------------------------------------------------
__global__ __launch_bounds__(256) void hist_kernel(
    const int* __restrict__ edst, int* __restrict__ deg, int E) {
  int i = (blockIdx.x * blockDim.x + threadIdx.x) * 4;
  if (i + 4 <= E) {
    int4 d = *(const int4*)(edst + i);
    atomicAdd(deg + d.x, 1);
    atomicAdd(deg + d.y, 1);
    atomicAdd(deg + d.z, 1);
    atomicAdd(deg + d.w, 1);
  } else {
    for (int k = i; k < E; ++k) atomicAdd(deg + edst[k], 1);
  }
}

// ---------------------------------------------------------------------------
// Pass B1: per-block (256-element) sums of deg -> bsum[b]
// ---------------------------------------------------------------------------
__global__ __launch_bounds__(256) void scan_reduce_kernel(
    const int* __restrict__ deg, int* __restrict__ bsum, int N) {
  __shared__ int ts[256];
  int t = threadIdx.x;
  int i = blockIdx.x * 256 + t;
  ts[t] = (i < N) ? deg[i] : 0;
  __syncthreads();
  for (int off = 128; off > 0; off >>= 1) {
    if (t < off) ts[t] += ts[t + off];
    __syncthreads();
  }
  if (t == 0) bsum[blockIdx.x] = ts[0];
}

// ---------------------------------------------------------------------------
// Pass B2: single block scans block sums (nb <= 256) -> exclusive boff[b]
// ---------------------------------------------------------------------------
__global__ __launch_bounds__(256) void scan_blocksums_kernel(
    const int* __restrict__ bsum, int* __restrict__ boff, int nb) {
  __shared__ int ts[256];
  int t = threadIdx.x;
  ts[t] = (t < nb) ? bsum[t] : 0;
  __syncthreads();
  for (int off = 1; off < 256; off <<= 1) {
    int v = (t >= off) ? ts[t - off] : 0;
    __syncthreads();
    ts[t] += v;
    __syncthreads();
  }
  if (t < nb) boff[t] = (t == 0) ? 0 : ts[t - 1];
}

// ---------------------------------------------------------------------------
// Pass B3: per-block 256-element scan + block offset -> cur (excl), offs (incl)
// ---------------------------------------------------------------------------
__global__ __launch_bounds__(256) void scan_final_kernel(
    const int* __restrict__ deg, const int* __restrict__ boff,
    int* __restrict__ cur, int* __restrict__ offs, int N) {
  __shared__ int ts[256];
  int t = threadIdx.x;
  int i = blockIdx.x * 256 + t;
  int v = (i < N) ? deg[i] : 0;
  ts[t] = v;
  __syncthreads();
  for (int off = 1; off < 256; off <<= 1) {
    int x = (t >= off) ? ts[t - off] : 0;
    __syncthreads();
    ts[t] += x;
    __syncthreads();
  }
  if (i < N) {
    int incl = ts[t] + boff[blockIdx.x];
    cur[i] = incl - v;
    offs[i] = incl;
  }
}

// ---------------------------------------------------------------------------
// Pass C: scatter edges into dst-sorted record array {src, coeff}.
// 4 edges / thread, vectorized loads.
// ---------------------------------------------------------------------------
__global__ __launch_bounds__(256) void scatter_kernel(
    const float* __restrict__ alpha, const float* __restrict__ ew,
    const int* __restrict__ node_id, const int* __restrict__ esrc,
    const int* __restrict__ edst, int* __restrict__ cur,
    int2* __restrict__ recs, int E, int gene_num) {
  int i = (blockIdx.x * blockDim.x + threadIdx.x) * 4;
  if (i >= E) return;
  if (i + 4 <= E) {
    int4 s4 = *(const int4*)(esrc + i);
    int4 d4 = *(const int4*)(edst + i);
    float4 w4 = *(const float4*)(ew + i);
    int ss[4] = {s4.x, s4.y, s4.z, s4.w};
    int dd[4] = {d4.x, d4.y, d4.z, d4.w};
    float ww[4] = {w4.x, w4.y, w4.z, w4.w};
#pragma unroll
    for (int k = 0; k < 4; ++k) {
      int sid = node_id[ss[k]];
      int did = node_id[dd[k]];
      int idx;
      if (sid >= 0) idx = (did >= 0) ? gene_num : sid;
      else          idx = (did >= 0) ? did : (gene_num + 1);
      float coeff = alpha[idx] * ww[k];
      int pos = atomicAdd(cur + dd[k], 1);
      recs[pos] = make_int2(ss[k], __float_as_int(coeff));
    }
  } else {
    for (int k = i; k < E; ++k) {
      int src = esrc[k], dst = edst[k];
      int sid = node_id[src], did = node_id[dst];
      int idx;
      if (sid >= 0) idx = (did >= 0) ? gene_num : sid;
      else          idx = (did >= 0) ? did : (gene_num + 1);
      float coeff = alpha[idx] * ew[k];
      int pos = atomicAdd(cur + dst, 1);
      recs[pos] = make_int2(src, __float_as_int(coeff));
    }
  }
}

// ---------------------------------------------------------------------------
// Pass D: one wave per dst node.  Lane l owns bf16 pair (dims 2l,2l+1).
// Wave stages up to 64 records into registers, broadcasts via shfl;
// inner loop unrolled x4 so 4 independent 256B-per-wave gathers are in
// flight.  f32 accumulate; writes the mean row once (f32 -> d_out).
// ---------------------------------------------------------------------------
__global__ __launch_bounds__(256) void accumulate_kernel(
    const unsigned short* __restrict__ h16, const int2* __restrict__ recs,
    const int* __restrict__ offs, float* __restrict__ neigh, int N) {
  int wid = (blockIdx.x * blockDim.x + threadIdx.x) >> 6;
  int l = threadIdx.x & 63;
  if (wid >= N) return;
  int start = (wid == 0) ? 0 : offs[wid - 1];
  int end = offs[wid];
  float ax = 0.f, ay = 0.f;
  const unsigned int* hp = ((const unsigned int*)h16) + l;  // row = 64 uints

  for (int i = start; i < end; i += 64) {
    int m = end - i;
    if (m > 64) m = 64;
    int2 r = make_int2(0, 0);
    if (l < m) r = recs[i + l];
    int k = 0;
    for (; k + 4 <= m; k += 4) {
      int s0 = __shfl(r.x, k + 0), s1 = __shfl(r.x, k + 1);
      int s2 = __shfl(r.x, k + 2), s3 = __shfl(r.x, k + 3);
      float c0 = __int_as_float(__shfl(r.y, k + 0));
      float c1 = __int_as_float(__shfl(r.y, k + 1));
      float c2 = __int_as_float(__shfl(r.y, k + 2));
      float c3 = __int_as_float(__shfl(r.y, k + 3));
      unsigned int v0 = hp[(size_t)s0 * 64];
      unsigned int v1 = hp[(size_t)s1 * 64];
      unsigned int v2 = hp[(size_t)s2 * 64];
      unsigned int v3 = hp[(size_t)s3 * 64];
      ax += c0 * __uint_as_float(v0 << 16);
      ay += c0 * __uint_as_float(v0 & 0xffff0000u);
      ax += c1 * __uint_as_float(v1 << 16);
      ay += c1 * __uint_as_float(v1 & 0xffff0000u);
      ax += c2 * __uint_as_float(v2 << 16);
      ay += c2 * __uint_as_float(v2 & 0xffff0000u);
      ax += c3 * __uint_as_float(v3 << 16);
      ay += c3 * __uint_as_float(v3 & 0xffff0000u);
    }
    for (; k < m; ++k) {
      int s = __shfl(r.x, k);
      float cf = __int_as_float(__shfl(r.y, k));
      unsigned int v = hp[(size_t)s * 64];
      ax += cf * __uint_as_float(v << 16);
      ay += cf * __uint_as_float(v & 0xffff0000u);
    }
  }
  int degn = end - start;
  float inv = 1.0f / (float)(degn > 0 ? degn : 1);
  ((float2*)neigh)[(size_t)wid * (D / 2) + l] = make_float2(ax * inv, ay * inv);
}

// ---------------------------------------------------------------------------
// MLP: out = relu(neigh @ W.T + b), in-place on d_out (neigh staged to LDS
// per block before any write).  W in LDS, XOR-swizzled; neigh rows padded.
// ---------------------------------------------------------------------------
__global__ __launch_bounds__(256) void mlp_kernel(
    const float* __restrict__ neigh, const float* __restrict__ W,
    const float* __restrict__ bias, float* __restrict__ out, int N) {
  __shared__ float4 Wl[64 * 32];     // 32 KB, col = d4 ^ (r&7)
  __shared__ float4 NBl[NB * 33];    // row stride 33 f4

  int t = threadIdx.x;
  int n0 = blockIdx.x * NB;

  for (int i = 0; i < (NB * 32) / 256; ++i) {
    int idx = t + i * 256;
    int n = idx >> 5, d4 = idx & 31;
    int ng = n0 + n;
    float4 v = make_float4(0.f, 0.f, 0.f, 0.f);
    if (ng < N) v = ((const float4*)neigh)[(size_t)ng * 32 + d4];
    NBl[n * 33 + d4] = v;
  }

  int jq = t & 15;
  int g = t >> 4;

  for (int jh = 0; jh < 2; ++jh) {
    __syncthreads();
    for (int i = 0; i < 8; ++i) {
      int idx = t + i * 256;
      int r = idx >> 5, d4 = idx & 31;
      float4 w = ((const float4*)W)[(size_t)(jh * 64 + r) * 32 + d4];
      Wl[r * 32 + (d4 ^ (r & 7))] = w;
    }
    __syncthreads();

    float acc[4][2];
#pragma unroll
    for (int jj = 0; jj < 4; ++jj)
#pragma unroll
      for (int nn = 0; nn < 2; ++nn) acc[jj][nn] = 0.f;

#pragma unroll 8
    for (int d4 = 0; d4 < 32; ++d4) {
      float4 nbv0 = NBl[(2 * g + 0) * 33 + d4];
      float4 nbv1 = NBl[(2 * g + 1) * 33 + d4];
#pragma unroll
      for (int jj = 0; jj < 4; ++jj) {
        int r = jq + 16 * jj;
        float4 w = Wl[r * 32 + (d4 ^ (r & 7))];
        acc[jj][0] += w.x * nbv0.x + w.y * nbv0.y + w.z * nbv0.z + w.w * nbv0.w;
        acc[jj][1] += w.x * nbv1.x + w.y * nbv1.y + w.z * nbv1.z + w.w * nbv1.w;
      }
    }

#pragma unroll
    for (int jj = 0; jj < 4; ++jj) {
      int j = jh * 64 + jq + 16 * jj;
      float bj = bias[j];
#pragma unroll
      for (int nn = 0; nn < 2; ++nn) {
        int ng = n0 + 2 * g + nn;
        if (ng < N) out[(size_t)ng * D + j] = fmaxf(acc[jj][nn] + bj, 0.0f);
      }
    }
  }
}

extern "C" void kernel_launch(void* const* d_in, const int* in_sizes, int n_in,
                              void* d_out, int out_size, void* d_ws, size_t ws_size,
                              hipStream_t stream) {
  const float* h     = (const float*)d_in[0];
  const float* alpha = (const float*)d_in[1];
  const float* ew    = (const float*)d_in[2];
  const float* W     = (const float*)d_in[3];
  const float* bias  = (const float*)d_in[4];
  const int* node_id = (const int*)d_in[5];
  const int* esrc    = (const int*)d_in[6];
  const int* edst    = (const int*)d_in[7];
  float* out = (float*)d_out;

  int E = in_sizes[2];
  int N = in_sizes[5];
  int gene_num = in_sizes[1] - 2;
  int nb = (N + 255) / 256;   // 196 for N=50000, must be <= 256

  // workspace layout
  int* deg  = (int*)d_ws;                       // N
  int* cur  = deg + N;                          // N
  int* offs = cur + N;                          // N
  int* bsum = offs + N;                         // 256
  int* boff = bsum + 256;                       // 256
  size_t h16_off = (((size_t)(3 * N) + 512) * sizeof(int) + 15) & ~(size_t)15;
  unsigned short* h16 = (unsigned short*)((char*)d_ws + h16_off);  // N*D bf16
  size_t rec_off = (h16_off + (size_t)N * D * sizeof(unsigned short) + 15) & ~(size_t)15;
  int2* recs = (int2*)((char*)d_ws + rec_off);  // E * 8B
  size_t need = rec_off + (size_t)E * sizeof(int2);
  if (ws_size < need) return;

  hipMemsetAsync(deg, 0, (size_t)N * sizeof(int), stream);

  {
    int total4 = N * D / 4;
    cvt_kernel<<<(total4 + 255) / 256, 256, 0, stream>>>(h, h16, total4);
  }
  {
    int blocks = (E / 4 + 255) / 256 + 1;
    hist_kernel<<<blocks, 256, 0, stream>>>(edst, deg, E);
  }
  scan_reduce_kernel<<<nb, 256, 0, stream>>>(deg, bsum, N);
  scan_blocksums_kernel<<<1, 256, 0, stream>>>(bsum, boff, nb);
  scan_final_kernel<<<nb, 256, 0, stream>>>(deg, boff, cur, offs, N);
  {
    int blocks = (E / 4 + 255) / 256 + 1;
    scatter_kernel<<<blocks, 256, 0, stream>>>(alpha, ew, node_id, esrc, edst,
                                               cur, recs, E, gene_num);
  }
  {
    long long total = (long long)N * 64;
    int blocks = (int)((total + 255) / 256);
    accumulate_kernel<<<blocks, 256, 0, stream>>>(h16, recs, offs, out, N);
  }
  {
    int blocks = (N + NB - 1) / NB;
    mlp_kernel<<<blocks, 256, 0, stream>>>(out, W, bias, out, N);
  }
}

// Round 5
// 177.329 us; speedup vs baseline: 10.1114x; 1.1920x over previous
//
#include <hip/hip_runtime.h>

#define D 128

typedef __attribute__((ext_vector_type(8))) short bf16x8;
typedef __attribute__((ext_vector_type(4))) float f32x4;

__device__ __forceinline__ unsigned short f2bf(float f) {
  unsigned int u = __float_as_uint(f);
  u = (u + 0x7fffu + ((u >> 16) & 1)) >> 16;
  return (unsigned short)u;
}

// ---------------------------------------------------------------------------
// Pass 0: convert h (f32) -> h16 (bf16, RNE).  4 elements / thread.
// ---------------------------------------------------------------------------
__global__ __launch_bounds__(256) void cvt_kernel(
    const float* __restrict__ h, unsigned short* __restrict__ h16, int total4) {
  int i = blockIdx.x * blockDim.x + threadIdx.x;
  if (i >= total4) return;
  float4 v = ((const float4*)h)[i];
  ushort4 o;
  o.x = f2bf(v.x); o.y = f2bf(v.y); o.z = f2bf(v.z); o.w = f2bf(v.w);
  ((ushort4*)h16)[i] = o;
}

// ---------------------------------------------------------------------------
// Pass A: histogram of edge destinations -> deg[dst].  4 edges / thread.
// ---------------------------------------------------------------------------
__global__ __launch_bounds__(256) void hist_kernel(
    const int* __restrict__ edst, int* __restrict__ deg, int E) {
  int i = (blockIdx.x * blockDim.x + threadIdx.x) * 4;
  if (i + 4 <= E) {
    int4 d = *(const int4*)(edst + i);
    atomicAdd(deg + d.x, 1);
    atomicAdd(deg + d.y, 1);
    atomicAdd(deg + d.z, 1);
    atomicAdd(deg + d.w, 1);
  } else {
    for (int k = i; k < E; ++k) atomicAdd(deg + edst[k], 1);
  }
}

// ---------------------------------------------------------------------------
// Pass B1: per-block (256-element) sums of deg -> bsum[b]
// ---------------------------------------------------------------------------
__global__ __launch_bounds__(256) void scan_reduce_kernel(
    const int* __restrict__ deg, int* __restrict__ bsum, int N) {
  __shared__ int ts[256];
  int t = threadIdx.x;
  int i = blockIdx.x * 256 + t;
  ts[t] = (i < N) ? deg[i] : 0;
  __syncthreads();
  for (int off = 128; off > 0; off >>= 1) {
    if (t < off) ts[t] += ts[t + off];
    __syncthreads();
  }
  if (t == 0) bsum[blockIdx.x] = ts[0];
}

// ---------------------------------------------------------------------------
// Pass B2: single block scans block sums (nb <= 256) -> exclusive boff[b]
// ---------------------------------------------------------------------------
__global__ __launch_bounds__(256) void scan_blocksums_kernel(
    const int* __restrict__ bsum, int* __restrict__ boff, int nb) {
  __shared__ int ts[256];
  int t = threadIdx.x;
  ts[t] = (t < nb) ? bsum[t] : 0;
  __syncthreads();
  for (int off = 1; off < 256; off <<= 1) {
    int v = (t >= off) ? ts[t - off] : 0;
    __syncthreads();
    ts[t] += v;
    __syncthreads();
  }
  if (t < nb) boff[t] = (t == 0) ? 0 : ts[t - 1];
}

// ---------------------------------------------------------------------------
// Pass B3: per-block 256-element scan + block offset -> cur (excl), offs (incl)
// ---------------------------------------------------------------------------
__global__ __launch_bounds__(256) void scan_final_kernel(
    const int* __restrict__ deg, const int* __restrict__ boff,
    int* __restrict__ cur, int* __restrict__ offs, int N) {
  __shared__ int ts[256];
  int t = threadIdx.x;
  int i = blockIdx.x * 256 + t;
  int v = (i < N) ? deg[i] : 0;
  ts[t] = v;
  __syncthreads();
  for (int off = 1; off < 256; off <<= 1) {
    int x = (t >= off) ? ts[t - off] : 0;
    __syncthreads();
    ts[t] += x;
    __syncthreads();
  }
  if (i < N) {
    int incl = ts[t] + boff[blockIdx.x];
    cur[i] = incl - v;
    offs[i] = incl;
  }
}

// ---------------------------------------------------------------------------
// Pass C: scatter edges into dst-sorted record array {src, coeff}.
// 4 edges / thread, vectorized loads.
// ---------------------------------------------------------------------------
__global__ __launch_bounds__(256) void scatter_kernel(
    const float* __restrict__ alpha, const float* __restrict__ ew,
    const int* __restrict__ node_id, const int* __restrict__ esrc,
    const int* __restrict__ edst, int* __restrict__ cur,
    int2* __restrict__ recs, int E, int gene_num) {
  int i = (blockIdx.x * blockDim.x + threadIdx.x) * 4;
  if (i >= E) return;
  if (i + 4 <= E) {
    int4 s4 = *(const int4*)(esrc + i);
    int4 d4 = *(const int4*)(edst + i);
    float4 w4 = *(const float4*)(ew + i);
    int ss[4] = {s4.x, s4.y, s4.z, s4.w};
    int dd[4] = {d4.x, d4.y, d4.z, d4.w};
    float ww[4] = {w4.x, w4.y, w4.z, w4.w};
#pragma unroll
    for (int k = 0; k < 4; ++k) {
      int sid = node_id[ss[k]];
      int did = node_id[dd[k]];
      int idx;
      if (sid >= 0) idx = (did >= 0) ? gene_num : sid;
      else          idx = (did >= 0) ? did : (gene_num + 1);
      float coeff = alpha[idx] * ww[k];
      int pos = atomicAdd(cur + dd[k], 1);
      recs[pos] = make_int2(ss[k], __float_as_int(coeff));
    }
  } else {
    for (int k = i; k < E; ++k) {
      int src = esrc[k], dst = edst[k];
      int sid = node_id[src], did = node_id[dst];
      int idx;
      if (sid >= 0) idx = (did >= 0) ? gene_num : sid;
      else          idx = (did >= 0) ? did : (gene_num + 1);
      float coeff = alpha[idx] * ew[k];
      int pos = atomicAdd(cur + dst, 1);
      recs[pos] = make_int2(src, __float_as_int(coeff));
    }
  }
}

// ---------------------------------------------------------------------------
// Pass D: one wave per dst node.  Lane l owns bf16 pair (dims 2l,2l+1).
// 4-deep unrolled gather pipeline; f32 accumulate; mean row -> d_out (f32).
// ---------------------------------------------------------------------------
__global__ __launch_bounds__(256) void accumulate_kernel(
    const unsigned short* __restrict__ h16, const int2* __restrict__ recs,
    const int* __restrict__ offs, float* __restrict__ neigh, int N) {
  int wid = (blockIdx.x * blockDim.x + threadIdx.x) >> 6;
  int l = threadIdx.x & 63;
  if (wid >= N) return;
  int start = (wid == 0) ? 0 : offs[wid - 1];
  int end = offs[wid];
  float ax = 0.f, ay = 0.f;
  const unsigned int* hp = ((const unsigned int*)h16) + l;  // row = 64 uints

  for (int i = start; i < end; i += 64) {
    int m = end - i;
    if (m > 64) m = 64;
    int2 r = make_int2(0, 0);
    if (l < m) r = recs[i + l];
    int k = 0;
    for (; k + 4 <= m; k += 4) {
      int s0 = __shfl(r.x, k + 0), s1 = __shfl(r.x, k + 1);
      int s2 = __shfl(r.x, k + 2), s3 = __shfl(r.x, k + 3);
      float c0 = __int_as_float(__shfl(r.y, k + 0));
      float c1 = __int_as_float(__shfl(r.y, k + 1));
      float c2 = __int_as_float(__shfl(r.y, k + 2));
      float c3 = __int_as_float(__shfl(r.y, k + 3));
      unsigned int v0 = hp[(size_t)s0 * 64];
      unsigned int v1 = hp[(size_t)s1 * 64];
      unsigned int v2 = hp[(size_t)s2 * 64];
      unsigned int v3 = hp[(size_t)s3 * 64];
      ax += c0 * __uint_as_float(v0 << 16);
      ay += c0 * __uint_as_float(v0 & 0xffff0000u);
      ax += c1 * __uint_as_float(v1 << 16);
      ay += c1 * __uint_as_float(v1 & 0xffff0000u);
      ax += c2 * __uint_as_float(v2 << 16);
      ay += c2 * __uint_as_float(v2 & 0xffff0000u);
      ax += c3 * __uint_as_float(v3 << 16);
      ay += c3 * __uint_as_float(v3 & 0xffff0000u);
    }
    for (; k < m; ++k) {
      int s = __shfl(r.x, k);
      float cf = __int_as_float(__shfl(r.y, k));
      unsigned int v = hp[(size_t)s * 64];
      ax += cf * __uint_as_float(v << 16);
      ay += cf * __uint_as_float(v & 0xffff0000u);
    }
  }
  int degn = end - start;
  float inv = 1.0f / (float)(degn > 0 ? degn : 1);
  ((float2*)neigh)[(size_t)wid * (D / 2) + l] = make_float2(ax * inv, ay * inv);
}

// ---------------------------------------------------------------------------
// MLP (MFMA): io = relu(io @ W.T + b), in place on d_out.
// Block = 256 thr = 4 waves, 64 rows/block (16/wave).  W converted to bf16
// and staged in LDS (32 KB) with 16B-chunk XOR swizzle (cb ^= row&7) so the
// strided row-major ds_read_b128 is conflict-light.  neigh f32 -> bf16 in
// regs.  mfma_f32_16x16x32_bf16; C/D: col=l&15, row=(l>>4)*4+r (m89).
// In-place safe: each wave reads only its own 16 rows (all A-frags loaded
// before any store); waves/blocks own disjoint rows.
// ---------------------------------------------------------------------------
__global__ __launch_bounds__(256) void mlp_mfma_kernel(
    const float* __restrict__ W, const float* __restrict__ bias,
    float* __restrict__ io, int N) {
  __shared__ __align__(16) unsigned short Wl[128 * 128];  // 32 KB bf16

  int t = threadIdx.x;
  // stage + convert W: 2048 16B-chunks (8 bf16), 8 per thread
#pragma unroll
  for (int i = 0; i < 8; ++i) {
    int chunk = t + 256 * i;          // 0..2047
    int row = chunk >> 4;             // W row (out feature j)
    int cb = chunk & 15;              // 16B chunk within row
    const float* gp = W + (size_t)row * 128 + cb * 8;
    float4 a = *(const float4*)gp;
    float4 b = *(const float4*)(gp + 4);
    bf16x8 v;
    v[0] = (short)f2bf(a.x); v[1] = (short)f2bf(a.y);
    v[2] = (short)f2bf(a.z); v[3] = (short)f2bf(a.w);
    v[4] = (short)f2bf(b.x); v[5] = (short)f2bf(b.y);
    v[6] = (short)f2bf(b.z); v[7] = (short)f2bf(b.w);
    *(bf16x8*)((char*)Wl + row * 256 + ((cb ^ (row & 7)) << 4)) = v;
  }
  __syncthreads();

  int l = t & 63;
  int w = t >> 6;
  int kg = l >> 4;                    // 0..3 k-group
  int m_base = blockIdx.x * 64 + w * 16;
  int arow = m_base + (l & 15);
  if (arow >= N) arow = N - 1;        // clamp (stores are guarded)

  // A fragments: lane holds neigh[arow][kk*32 + kg*8 .. +7] as bf16
  bf16x8 af[4];
  const float* ap = io + (size_t)arow * 128 + kg * 8;
#pragma unroll
  for (int kk = 0; kk < 4; ++kk) {
    float4 a = *(const float4*)(ap + kk * 32);
    float4 b = *(const float4*)(ap + kk * 32 + 4);
    bf16x8 v;
    v[0] = (short)f2bf(a.x); v[1] = (short)f2bf(a.y);
    v[2] = (short)f2bf(a.z); v[3] = (short)f2bf(a.w);
    v[4] = (short)f2bf(b.x); v[5] = (short)f2bf(b.y);
    v[6] = (short)f2bf(b.z); v[7] = (short)f2bf(b.w);
    af[kk] = v;
  }

#pragma unroll
  for (int c = 0; c < 8; ++c) {
    f32x4 acc = {0.f, 0.f, 0.f, 0.f};
    int row_w = c * 16 + (l & 15);    // W row = out feature j
    int rs = row_w & 7;
#pragma unroll
    for (int kk = 0; kk < 4; ++kk) {
      int cb = kk * 4 + kg;
      bf16x8 bf = *(bf16x8*)((char*)Wl + row_w * 256 + ((cb ^ rs) << 4));
      acc = __builtin_amdgcn_mfma_f32_16x16x32_bf16(af[kk], bf, acc, 0, 0, 0);
    }
    int j = c * 16 + (l & 15);
    float bj = bias[j];
#pragma unroll
    for (int r = 0; r < 4; ++r) {
      int m = m_base + kg * 4 + r;
      if (m < N) io[(size_t)m * 128 + j] = fmaxf(acc[r] + bj, 0.0f);
    }
  }
}

extern "C" void kernel_launch(void* const* d_in, const int* in_sizes, int n_in,
                              void* d_out, int out_size, void* d_ws, size_t ws_size,
                              hipStream_t stream) {
  const float* h     = (const float*)d_in[0];
  const float* alpha = (const float*)d_in[1];
  const float* ew    = (const float*)d_in[2];
  const float* W     = (const float*)d_in[3];
  const float* bias  = (const float*)d_in[4];
  const int* node_id = (const int*)d_in[5];
  const int* esrc    = (const int*)d_in[6];
  const int* edst    = (const int*)d_in[7];
  float* out = (float*)d_out;

  int E = in_sizes[2];
  int N = in_sizes[5];
  int gene_num = in_sizes[1] - 2;
  int nb = (N + 255) / 256;   // 196 for N=50000, must be <= 256

  // workspace layout
  int* deg  = (int*)d_ws;                       // N
  int* cur  = deg + N;                          // N
  int* offs = cur + N;                          // N
  int* bsum = offs + N;                         // 256
  int* boff = bsum + 256;                       // 256
  size_t h16_off = (((size_t)(3 * N) + 512) * sizeof(int) + 15) & ~(size_t)15;
  unsigned short* h16 = (unsigned short*)((char*)d_ws + h16_off);  // N*D bf16
  size_t rec_off = (h16_off + (size_t)N * D * sizeof(unsigned short) + 15) & ~(size_t)15;
  int2* recs = (int2*)((char*)d_ws + rec_off);  // E * 8B
  size_t need = rec_off + (size_t)E * sizeof(int2);
  if (ws_size < need) return;

  hipMemsetAsync(deg, 0, (size_t)N * sizeof(int), stream);

  {
    int total4 = N * D / 4;
    cvt_kernel<<<(total4 + 255) / 256, 256, 0, stream>>>(h, h16, total4);
  }
  {
    int blocks = (E / 4 + 255) / 256 + 1;
    hist_kernel<<<blocks, 256, 0, stream>>>(edst, deg, E);
  }
  scan_reduce_kernel<<<nb, 256, 0, stream>>>(deg, bsum, N);
  scan_blocksums_kernel<<<1, 256, 0, stream>>>(bsum, boff, nb);
  scan_final_kernel<<<nb, 256, 0, stream>>>(deg, boff, cur, offs, N);
  {
    int blocks = (E / 4 + 255) / 256 + 1;
    scatter_kernel<<<blocks, 256, 0, stream>>>(alpha, ew, node_id, esrc, edst,
                                               cur, recs, E, gene_num);
  }
  {
    long long total = (long long)N * 64;
    int blocks = (int)((total + 255) / 256);
    accumulate_kernel<<<blocks, 256, 0, stream>>>(h16, recs, offs, out, N);
  }
  {
    int blocks = (N + 63) / 64;
    mlp_mfma_kernel<<<blocks, 256, 0, stream>>>(W, bias, out, N);
  }
}